// Round 1
// baseline (232.846 us; speedup 1.0000x reference)
//
#include <hip/hip_runtime.h>

// FeatureVoxel4D: factorized quadlinear interpolation over 6 rank-F planes.
// planes: [F=4][193][193][C=16] float32. positions: [N,4]. out: [N,16].
//
// Factorization: sum_k w_k * A[f,i_k,j_k,c]*B[f,k_k,l_k,c]
//   = (bilerp_A[f,c]) * (bilerp_B[f,c])   since w_k is a product of per-dim
// weights and A/B each depend on disjoint dim pairs.

#define F_STRIDE (193 * 193 * 16)  // plane f-stride in floats
#define ROW_STRIDE (193 * 16)      // plane i-stride in floats

__global__ __launch_bounds__(256) void fv4d_kernel(
    const float* __restrict__ pos,
    const float* __restrict__ ptx,
    const float* __restrict__ pty,
    const float* __restrict__ ptz,
    const float* __restrict__ pxy,
    const float* __restrict__ pxz,
    const float* __restrict__ pyz,
    const float* __restrict__ coord_range,  // [2][4] lo row then hi row
    const float* __restrict__ resolution,   // [4]
    float* __restrict__ out,                // [N][16]
    int N)
{
    const int g = blockIdx.x * 256 + threadIdx.x;
    const int n = g >> 4;
    const int c = g & 15;
    if (n >= N) return;

    const float4 p4 = *reinterpret_cast<const float4*>(pos + (size_t)n * 4);

    const float lo0 = coord_range[0], lo1 = coord_range[1], lo2 = coord_range[2], lo3 = coord_range[3];
    const float hi0 = coord_range[4], hi1 = coord_range[5], hi2 = coord_range[6], hi3 = coord_range[7];
    const float r0 = resolution[0], r1 = resolution[1], r2 = resolution[2], r3 = resolution[3];

    // normalize to [0,1) and mask (same op order as reference)
    float pt = (p4.x - lo0) / (hi0 - lo0);
    float px = (p4.y - lo1) / (hi1 - lo1);
    float py = (p4.z - lo2) / (hi2 - lo2);
    float pz = (p4.w - lo3) / (hi3 - lo3);

    const bool inr = (pt >= 0.f) && (pt < 1.f) && (px >= 0.f) && (px < 1.f)
                  && (py >= 0.f) && (py < 1.f) && (pz >= 0.f) && (pz < 1.f);

    pt *= r0; px *= r1; py *= r2; pz *= r3;

    const int bt = min(max((int)floorf(pt), 0), (int)r0 - 1);
    const int bx = min(max((int)floorf(px), 0), (int)r1 - 1);
    const int by = min(max((int)floorf(py), 0), (int)r2 - 1);
    const int bz = min(max((int)floorf(pz), 0), (int)r3 - 1);

    const float ft = pt - (float)bt, fx = px - (float)bx;
    const float fy = py - (float)by, fz = pz - (float)bz;
    const float gt = 1.f - ft, gx = 1.f - fx, gy = 1.f - fy, gz = 1.f - fz;

    // bilinear weights per plane: plane(i,j) -> w00=gi*gj w01=gi*fj w10=fi*gj w11=fi*fj
    // tx:(t,x)  yz:(y,z)  ty:(t,y)  xz:(x,z)  tz:(t,z)  xy:(x,y)
    const float wtx00 = gt * gx, wtx01 = gt * fx, wtx10 = ft * gx, wtx11 = ft * fx;
    const float wyz00 = gy * gz, wyz01 = gy * fz, wyz10 = fy * gz, wyz11 = fy * fz;
    const float wty00 = gt * gy, wty01 = gt * fy, wty10 = ft * gy, wty11 = ft * fy;
    const float wxz00 = gx * gz, wxz01 = gx * fz, wxz10 = fx * gz, wxz11 = fx * fz;
    const float wtz00 = gt * gz, wtz01 = gt * fz, wtz10 = ft * gz, wtz11 = ft * fz;
    const float wxy00 = gx * gy, wxy01 = gx * fy, wxy10 = fx * gy, wxy11 = fx * fy;

    // base offsets (channel c), taps at +0, +16 (j+1), +ROW_STRIDE (i+1), +ROW_STRIDE+16
    const int otx = (bt * 193 + bx) * 16 + c;
    const int oyz = (by * 193 + bz) * 16 + c;
    const int oty = (bt * 193 + by) * 16 + c;
    const int oxz = (bx * 193 + bz) * 16 + c;
    const int otz = (bt * 193 + bz) * 16 + c;
    const int oxy = (bx * 193 + by) * 16 + c;

    float acc = 0.f;
#pragma unroll
    for (int f = 0; f < 4; ++f) {
        const int fo = f * F_STRIDE;
        const float atx = ptx[fo + otx] * wtx00 + ptx[fo + otx + 16] * wtx01
                        + ptx[fo + otx + ROW_STRIDE] * wtx10 + ptx[fo + otx + ROW_STRIDE + 16] * wtx11;
        const float ayz = pyz[fo + oyz] * wyz00 + pyz[fo + oyz + 16] * wyz01
                        + pyz[fo + oyz + ROW_STRIDE] * wyz10 + pyz[fo + oyz + ROW_STRIDE + 16] * wyz11;
        const float aty = pty[fo + oty] * wty00 + pty[fo + oty + 16] * wty01
                        + pty[fo + oty + ROW_STRIDE] * wty10 + pty[fo + oty + ROW_STRIDE + 16] * wty11;
        const float axz = pxz[fo + oxz] * wxz00 + pxz[fo + oxz + 16] * wxz01
                        + pxz[fo + oxz + ROW_STRIDE] * wxz10 + pxz[fo + oxz + ROW_STRIDE + 16] * wxz11;
        const float atz = ptz[fo + otz] * wtz00 + ptz[fo + otz + 16] * wtz01
                        + ptz[fo + otz + ROW_STRIDE] * wtz10 + ptz[fo + otz + ROW_STRIDE + 16] * wtz11;
        const float axy = pxy[fo + oxy] * wxy00 + pxy[fo + oxy + 16] * wxy01
                        + pxy[fo + oxy + ROW_STRIDE] * wxy10 + pxy[fo + oxy + ROW_STRIDE + 16] * wxy11;
        acc += atx * ayz + aty * axz + atz * axy;
    }

    out[(size_t)n * 16 + c] = inr ? acc : 0.f;
}

extern "C" void kernel_launch(void* const* d_in, const int* in_sizes, int n_in,
                              void* d_out, int out_size, void* d_ws, size_t ws_size,
                              hipStream_t stream) {
    const float* pos = (const float*)d_in[0];
    const float* ptx = (const float*)d_in[1];
    const float* pty = (const float*)d_in[2];
    const float* ptz = (const float*)d_in[3];
    const float* pxy = (const float*)d_in[4];
    const float* pxz = (const float*)d_in[5];
    const float* pyz = (const float*)d_in[6];
    const float* crange = (const float*)d_in[7];
    const float* resol = (const float*)d_in[8];
    float* out = (float*)d_out;

    const int N = in_sizes[0] / 4;
    const int total = N * 16;
    const int blocks = (total + 255) / 256;
    fv4d_kernel<<<blocks, 256, 0, stream>>>(pos, ptx, pty, ptz, pxy, pxz, pyz,
                                            crange, resol, out, N);
}

// Round 2
// 143.212 us; speedup vs baseline: 1.6259x; 1.6259x over previous
//
#include <hip/hip_runtime.h>

// FeatureVoxel4D: factorized quadlinear interpolation over 6 rank-F planes.
// planes: [F=4][193][193][C=16] float32. positions: [N,4]. out: [N,16].
//
// R2: counting-sort points by coarse 4D bucket (8 divisions/dim, 4096 bins) so
// that points processed together share plane cache lines in the per-XCD L2,
// plus bijective XCD-chunked block swizzle. Bucket footprint ~1MB << 4MB L2.

#define F_STRIDE (193 * 193 * 16)  // plane f-stride in floats
#define ROW_STRIDE (193 * 16)      // plane i-stride in floats
#define NBINS 4096

// ---- workspace layout (bytes) ----
// hist  : int[4096]    @ 0
// offs  : int[4096]    @ 16384
// key   : int[N]       @ 32768
// idx_s : int[N]       @ 32768 + 4N
// pos_s : float4[N]    @ 32768 + 8N   (16B aligned: 32768+8*200000 = 1632768)

__device__ __forceinline__ void pos_to_base(
    float4 p4, const float* cr, const float* res,
    int& bt, int& bx, int& by, int& bz,
    float& ft, float& fx, float& fy, float& fz, bool& inr)
{
    const float lo0 = cr[0], lo1 = cr[1], lo2 = cr[2], lo3 = cr[3];
    const float hi0 = cr[4], hi1 = cr[5], hi2 = cr[6], hi3 = cr[7];
    const float r0 = res[0], r1 = res[1], r2 = res[2], r3 = res[3];

    float pt = (p4.x - lo0) / (hi0 - lo0);
    float px = (p4.y - lo1) / (hi1 - lo1);
    float py = (p4.z - lo2) / (hi2 - lo2);
    float pz = (p4.w - lo3) / (hi3 - lo3);

    inr = (pt >= 0.f) && (pt < 1.f) && (px >= 0.f) && (px < 1.f)
       && (py >= 0.f) && (py < 1.f) && (pz >= 0.f) && (pz < 1.f);

    pt *= r0; px *= r1; py *= r2; pz *= r3;

    bt = min(max((int)floorf(pt), 0), (int)r0 - 1);
    bx = min(max((int)floorf(px), 0), (int)r1 - 1);
    by = min(max((int)floorf(py), 0), (int)r2 - 1);
    bz = min(max((int)floorf(pz), 0), (int)r3 - 1);

    ft = pt - (float)bt; fx = px - (float)bx;
    fy = py - (float)by; fz = pz - (float)bz;
}

__global__ __launch_bounds__(256) void k_init(int* hist) {
    hist[blockIdx.x * 256 + threadIdx.x] = 0;
}

__global__ __launch_bounds__(256) void k_hist(
    const float* __restrict__ pos, const float* __restrict__ cr,
    const float* __restrict__ res, int* __restrict__ key,
    int* __restrict__ hist, int N)
{
    const int i = blockIdx.x * 256 + threadIdx.x;
    if (i >= N) return;
    const float4 p4 = *reinterpret_cast<const float4*>(pos + (size_t)i * 4);
    int bt, bx, by, bz; float ft, fx, fy, fz; bool inr;
    pos_to_base(p4, cr, res, bt, bx, by, bz, ft, fx, fy, fz, inr);
    // 24 cells per bucket per dim (192/8)
    const int b = ((bt / 24) * 8 + (bx / 24)) * 64 + (by / 24) * 8 + (bz / 24);
    key[i] = b;
    atomicAdd(&hist[b], 1);
}

__global__ __launch_bounds__(256) void k_scan(const int* __restrict__ hist,
                                              int* __restrict__ offs)
{
    __shared__ int part[256];
    const int t = threadIdx.x;
    int loc[16];
    int s = 0;
    const int base = t * 16;
#pragma unroll
    for (int j = 0; j < 16; ++j) { loc[j] = s; s += hist[base + j]; }
    part[t] = s;
    __syncthreads();
    // Hillis-Steele inclusive scan over 256 partials
    for (int d = 1; d < 256; d <<= 1) {
        int v = (t >= d) ? part[t - d] : 0;
        __syncthreads();
        part[t] += v;
        __syncthreads();
    }
    const int excl = (t == 0) ? 0 : part[t - 1];
#pragma unroll
    for (int j = 0; j < 16; ++j) offs[base + j] = excl + loc[j];
}

__global__ __launch_bounds__(256) void k_scatter(
    const float* __restrict__ pos, const int* __restrict__ key,
    int* __restrict__ offs, float4* __restrict__ pos_s,
    int* __restrict__ idx_s, int N)
{
    const int i = blockIdx.x * 256 + threadIdx.x;
    if (i >= N) return;
    const int b = key[i];
    const int o = atomicAdd(&offs[b], 1);
    pos_s[o] = *reinterpret_cast<const float4*>(pos + (size_t)i * 4);
    idx_s[o] = i;
}

__global__ __launch_bounds__(256) void fv4d_sorted(
    const float4* __restrict__ pos_s,
    const int* __restrict__ idx_s,
    const float* __restrict__ ptx,
    const float* __restrict__ pty,
    const float* __restrict__ ptz,
    const float* __restrict__ pxy,
    const float* __restrict__ pxz,
    const float* __restrict__ pyz,
    const float* __restrict__ cr,
    const float* __restrict__ res,
    float* __restrict__ out,
    int N)
{
    // bijective XCD-chunked swizzle (m204): consecutive sorted points -> same XCD
    const int nwg = gridDim.x;
    const int q = nwg >> 3, r = nwg & 7;
    const int xcd = blockIdx.x & 7, j = blockIdx.x >> 3;
    const int sb = (xcd < r ? xcd * (q + 1) : r * (q + 1) + (xcd - r) * q) + j;

    const int n = sb * 16 + (threadIdx.x >> 4);
    const int c = threadIdx.x & 15;
    if (n >= N) return;

    const float4 p4 = pos_s[n];
    int bt, bx, by, bz; float ft, fx, fy, fz; bool inr;
    pos_to_base(p4, cr, res, bt, bx, by, bz, ft, fx, fy, fz, inr);
    const float gt = 1.f - ft, gx = 1.f - fx, gy = 1.f - fy, gz = 1.f - fz;

    const float wtx00 = gt * gx, wtx01 = gt * fx, wtx10 = ft * gx, wtx11 = ft * fx;
    const float wyz00 = gy * gz, wyz01 = gy * fz, wyz10 = fy * gz, wyz11 = fy * fz;
    const float wty00 = gt * gy, wty01 = gt * fy, wty10 = ft * gy, wty11 = ft * fy;
    const float wxz00 = gx * gz, wxz01 = gx * fz, wxz10 = fx * gz, wxz11 = fx * fz;
    const float wtz00 = gt * gz, wtz01 = gt * fz, wtz10 = ft * gz, wtz11 = ft * fz;
    const float wxy00 = gx * gy, wxy01 = gx * fy, wxy10 = fx * gy, wxy11 = fx * fy;

    const int otx = (bt * 193 + bx) * 16 + c;
    const int oyz = (by * 193 + bz) * 16 + c;
    const int oty = (bt * 193 + by) * 16 + c;
    const int oxz = (bx * 193 + bz) * 16 + c;
    const int otz = (bt * 193 + bz) * 16 + c;
    const int oxy = (bx * 193 + by) * 16 + c;

    float acc = 0.f;
#pragma unroll
    for (int f = 0; f < 4; ++f) {
        const int fo = f * F_STRIDE;
        const float atx = ptx[fo + otx] * wtx00 + ptx[fo + otx + 16] * wtx01
                        + ptx[fo + otx + ROW_STRIDE] * wtx10 + ptx[fo + otx + ROW_STRIDE + 16] * wtx11;
        const float ayz = pyz[fo + oyz] * wyz00 + pyz[fo + oyz + 16] * wyz01
                        + pyz[fo + oyz + ROW_STRIDE] * wyz10 + pyz[fo + oyz + ROW_STRIDE + 16] * wyz11;
        const float aty = pty[fo + oty] * wty00 + pty[fo + oty + 16] * wty01
                        + pty[fo + oty + ROW_STRIDE] * wty10 + pty[fo + oty + ROW_STRIDE + 16] * wty11;
        const float axz = pxz[fo + oxz] * wxz00 + pxz[fo + oxz + 16] * wxz01
                        + pxz[fo + oxz + ROW_STRIDE] * wxz10 + pxz[fo + oxz + ROW_STRIDE + 16] * wxz11;
        const float atz = ptz[fo + otz] * wtz00 + ptz[fo + otz + 16] * wtz01
                        + ptz[fo + otz + ROW_STRIDE] * wtz10 + ptz[fo + otz + ROW_STRIDE + 16] * wtz11;
        const float axy = pxy[fo + oxy] * wxy00 + pxy[fo + oxy + 16] * wxy01
                        + pxy[fo + oxy + ROW_STRIDE] * wxy10 + pxy[fo + oxy + ROW_STRIDE + 16] * wxy11;
        acc += atx * ayz + aty * axz + atz * axy;
    }

    const int orig = idx_s[n];
    out[(size_t)orig * 16 + c] = inr ? acc : 0.f;
}

// fallback (unsorted) kernel, used only if ws_size is too small
__global__ __launch_bounds__(256) void fv4d_plain(
    const float* __restrict__ pos,
    const float* __restrict__ ptx, const float* __restrict__ pty,
    const float* __restrict__ ptz, const float* __restrict__ pxy,
    const float* __restrict__ pxz, const float* __restrict__ pyz,
    const float* __restrict__ cr, const float* __restrict__ res,
    float* __restrict__ out, int N)
{
    const int g = blockIdx.x * 256 + threadIdx.x;
    const int n = g >> 4;
    const int c = g & 15;
    if (n >= N) return;
    const float4 p4 = *reinterpret_cast<const float4*>(pos + (size_t)n * 4);
    int bt, bx, by, bz; float ft, fx, fy, fz; bool inr;
    pos_to_base(p4, cr, res, bt, bx, by, bz, ft, fx, fy, fz, inr);
    const float gt = 1.f - ft, gx = 1.f - fx, gy = 1.f - fy, gz = 1.f - fz;
    const float wtx00 = gt * gx, wtx01 = gt * fx, wtx10 = ft * gx, wtx11 = ft * fx;
    const float wyz00 = gy * gz, wyz01 = gy * fz, wyz10 = fy * gz, wyz11 = fy * fz;
    const float wty00 = gt * gy, wty01 = gt * fy, wty10 = ft * gy, wty11 = ft * fy;
    const float wxz00 = gx * gz, wxz01 = gx * fz, wxz10 = fx * gz, wxz11 = fx * fz;
    const float wtz00 = gt * gz, wtz01 = gt * fz, wtz10 = ft * gz, wtz11 = ft * fz;
    const float wxy00 = gx * gy, wxy01 = gx * fy, wxy10 = fx * gy, wxy11 = fx * fy;
    const int otx = (bt * 193 + bx) * 16 + c;
    const int oyz = (by * 193 + bz) * 16 + c;
    const int oty = (bt * 193 + by) * 16 + c;
    const int oxz = (bx * 193 + bz) * 16 + c;
    const int otz = (bt * 193 + bz) * 16 + c;
    const int oxy = (bx * 193 + by) * 16 + c;
    float acc = 0.f;
#pragma unroll
    for (int f = 0; f < 4; ++f) {
        const int fo = f * F_STRIDE;
        acc += (ptx[fo + otx] * wtx00 + ptx[fo + otx + 16] * wtx01
              + ptx[fo + otx + ROW_STRIDE] * wtx10 + ptx[fo + otx + ROW_STRIDE + 16] * wtx11)
             * (pyz[fo + oyz] * wyz00 + pyz[fo + oyz + 16] * wyz01
              + pyz[fo + oyz + ROW_STRIDE] * wyz10 + pyz[fo + oyz + ROW_STRIDE + 16] * wyz11)
             + (pty[fo + oty] * wty00 + pty[fo + oty + 16] * wty01
              + pty[fo + oty + ROW_STRIDE] * wty10 + pty[fo + oty + ROW_STRIDE + 16] * wty11)
             * (pxz[fo + oxz] * wxz00 + pxz[fo + oxz + 16] * wxz01
              + pxz[fo + oxz + ROW_STRIDE] * wxz10 + pxz[fo + oxz + ROW_STRIDE + 16] * wxz11)
             + (ptz[fo + otz] * wtz00 + ptz[fo + otz + 16] * wtz01
              + ptz[fo + otz + ROW_STRIDE] * wtz10 + ptz[fo + otz + ROW_STRIDE + 16] * wtz11)
             * (pxy[fo + oxy] * wxy00 + pxy[fo + oxy + 16] * wxy01
              + pxy[fo + oxy + ROW_STRIDE] * wxy10 + pxy[fo + oxy + ROW_STRIDE + 16] * wxy11);
    }
    out[(size_t)n * 16 + c] = inr ? acc : 0.f;
}

extern "C" void kernel_launch(void* const* d_in, const int* in_sizes, int n_in,
                              void* d_out, int out_size, void* d_ws, size_t ws_size,
                              hipStream_t stream) {
    const float* pos = (const float*)d_in[0];
    const float* ptx = (const float*)d_in[1];
    const float* pty = (const float*)d_in[2];
    const float* ptz = (const float*)d_in[3];
    const float* pxy = (const float*)d_in[4];
    const float* pxz = (const float*)d_in[5];
    const float* pyz = (const float*)d_in[6];
    const float* cr  = (const float*)d_in[7];
    const float* res = (const float*)d_in[8];
    float* out = (float*)d_out;

    const int N = in_sizes[0] / 4;
    const size_t need = 32768 + (size_t)8 * N + (size_t)16 * N;

    if (ws_size < need) {
        const int blocks = (N * 16 + 255) / 256;
        fv4d_plain<<<blocks, 256, 0, stream>>>(pos, ptx, pty, ptz, pxy, pxz, pyz,
                                               cr, res, out, N);
        return;
    }

    char* ws = (char*)d_ws;
    int*    hist  = (int*)(ws);
    int*    offs  = (int*)(ws + 16384);
    int*    key   = (int*)(ws + 32768);
    int*    idx_s = (int*)(ws + 32768 + (size_t)4 * N);
    float4* pos_s = (float4*)(ws + 32768 + (size_t)8 * N);

    const int pb = (N + 255) / 256;
    k_init<<<NBINS / 256, 256, 0, stream>>>(hist);
    k_hist<<<pb, 256, 0, stream>>>(pos, cr, res, key, hist, N);
    k_scan<<<1, 256, 0, stream>>>(hist, offs);
    k_scatter<<<pb, 256, 0, stream>>>(pos, key, offs, pos_s, idx_s, N);

    const int blocks = (N * 16 + 255) / 256;
    fv4d_sorted<<<blocks, 256, 0, stream>>>(pos_s, idx_s, ptx, pty, ptz, pxy, pxz, pyz,
                                            cr, res, out, N);
}